// Round 10
// baseline (86.530 us; speedup 1.0000x reference)
//
#include <hip/hip_runtime.h>
#include <stdint.h>

// Segmented kNN graph: M=65536 pts, D=16, 64 segments x 1024 pts, K=16.
// Output: int32 src[M*16] then int32 dst[M*16].
//
// v10 = v9 arithmetic (quad-min pre-reduction + repair), restructured for
// latency hiding. Evidence r8->r9: op cuts stopped helping at ~37.5us kernel
// (VALUBusy ~57% at 4 waves/EU) -> stall-bound. Changes:
//  - 512-thr blocks (8 waves = 4 query-groups x 2 candidate-halves), grid
//    1024; LDS 42.25KB -> 3 blocks/CU = 6 waves/EU (was 4).
//  - launch_bounds(512,6): VGPR cap 85 (v7's (512,8) cap 64 caused spills).
//  - per wave just 2 iters of 256 cands; sort16(P0) || sort16(P1) give dual
//    independent chains, one keep16 (serial A-chain 4 -> 1 deep).
//  - cross-wave merge via dedicated 4.25KB LDS buffer; h==0 waves repair+write.
// Keys: f32 bits of (|c|^2+128-2<c,q>) | 10-bit idx (order-preserving, kf>0).
// MFMA 16x16x16f16 with C operand = biased norms.

#define L_SEG 1024
#define M_PTS 65536

typedef __fp16 fp16x2 __attribute__((ext_vector_type(2)));
typedef __fp16 fp16x4 __attribute__((ext_vector_type(4)));
typedef float  f32x4  __attribute__((ext_vector_type(4)));

__device__ __forceinline__ uint32_t umn(uint32_t a, uint32_t b) { return a < b ? a : b; }
__device__ __forceinline__ uint32_t umx(uint32_t a, uint32_t b) { return a > b ? a : b; }

#define CE(arr, i, p) { uint32_t lo = umn(arr[i], arr[p]); uint32_t hi = umx(arr[i], arr[p]); arr[i] = lo; arr[p] = hi; }

// bitonic clean of 16 (input bitonic, output sorted ascending): 32 CEs
__device__ __forceinline__ void clean16(uint32_t* A) {
    #pragma unroll
    for (int j = 8; j > 0; j >>= 1) {
        #pragma unroll
        for (int i = 0; i < 16; ++i) {
            int p = i ^ j;
            if (p > i) CE(A, i, p);
        }
    }
}

// Batcher odd-even mergesort-16, ascending (63 CEs)
__device__ __forceinline__ void sort16(uint32_t* B) {
    #pragma unroll
    for (int p = 1; p < 16; p <<= 1) {
        #pragma unroll
        for (int k = p; k >= 1; k >>= 1) {
            #pragma unroll
            for (int j = (k & (p - 1)); j + k < 16; j += 2 * k) {
                #pragma unroll
                for (int i = 0; i <= ((k - 1 < 15 - j - k) ? k - 1 : 15 - j - k); ++i) {
                    if ((i + j) / (2 * p) == (i + j + k) / (2 * p)) CE(B, i + j, i + j + k);
                }
            }
        }
    }
}

// merge sorted S into sorted A, keep lowest 16
__device__ __forceinline__ void keep16(uint32_t* A, const uint32_t* S) {
    #pragma unroll
    for (int i = 0; i < 16; ++i) A[i] = umn(A[i], S[15 - i]);
    clean16(A);
}

// cross-lane merges over g (xor 16 then 32): disjoint contents per lane
__device__ __forceinline__ void mergeg(uint32_t* A) {
    #pragma unroll
    for (int m = 16; m <= 32; m <<= 1) {
        uint32_t P[16];
        #pragma unroll
        for (int i = 0; i < 16; ++i) P[i] = (uint32_t)__shfl_xor((int)A[15 - i], m, 64);
        #pragma unroll
        for (int i = 0; i < 16; ++i) A[i] = umn(A[i], P[i]);
        clean16(A);
    }
}

__device__ __forceinline__ uint32_t sel4(const uint32_t* A, int g, int v) {
    uint32_t t01 = (g & 1) ? A[4 + v]  : A[v];
    uint32_t t23 = (g & 1) ? A[12 + v] : A[8 + v];
    return (g & 2) ? t23 : t01;
}

__global__ __launch_bounds__(512, 6) void knn_v10_kernel(const float* __restrict__ x,
                                                         int* __restrict__ out) {
    __shared__ __attribute__((aligned(16))) __fp16   sc[L_SEG * 16];   // -2*c, [cand][dim], 32KB
    __shared__ __attribute__((aligned(16))) float    ssq[L_SEG];       // |c|^2 + 128 (f32)
    __shared__ __attribute__((aligned(16))) __fp16   sq16[64 * 16];    // block's 64 queries, f16
    __shared__ __attribute__((aligned(16))) uint32_t smerge[64][17];   // cross-wave merge (4.25KB)

    const int tid = threadIdx.x;
    const int b   = blockIdx.x;
    const int seg = (b & 7) * 8 + (b >> 7);  // XCD swizzle, bijective
    const int qp  = (b >> 3) & 15;
    const float* xseg = x + (size_t)seg * (L_SEG * 16);
    const f32x4* gx4  = (const f32x4*)xseg;

    // ---- stage coords * -2 as f16, [cand][dim] layout (512 thr, 8 iters) ----
    {
        fp16x4* scv = (fp16x4*)sc;
        #pragma unroll
        for (int i = 0; i < 8; ++i) {
            f32x4 v = gx4[tid + 512 * i];
            union { fp16x2 h2[2]; fp16x4 h4; } u;
            u.h2[0] = __builtin_amdgcn_cvt_pkrtz(-2.0f * v[0], -2.0f * v[1]);
            u.h2[1] = __builtin_amdgcn_cvt_pkrtz(-2.0f * v[2], -2.0f * v[3]);
            scv[tid + 512 * i] = u.h4;
        }
    }
    // ---- stage biased norms (f32 from global): 2 cands per thread ----
    {
        const int c0 = tid << 1;
        #pragma unroll
        for (int c = 0; c < 2; ++c) {
            float s = 128.0f;
            #pragma unroll
            for (int d = 0; d < 4; ++d) {
                f32x4 v = gx4[(c0 + c) * 4 + d];
                s = __builtin_fmaf(v[0], v[0], s);
                s = __builtin_fmaf(v[1], v[1], s);
                s = __builtin_fmaf(v[2], v[2], s);
                s = __builtin_fmaf(v[3], v[3], s);
            }
            ssq[c0 + c] = s;
        }
    }
    // ---- stage this block's 64 queries (unscaled f16) ----
    if (tid < 64) {
        const f32x4* qg = gx4 + (size_t)(qp * 64 + tid) * 4;
        fp16x4* dst = (fp16x4*)(sq16 + (size_t)tid * 16);
        #pragma unroll
        for (int d = 0; d < 4; ++d) {
            f32x4 v = qg[d];
            union { fp16x2 h2[2]; fp16x4 h4; } u;
            u.h2[0] = __builtin_amdgcn_cvt_pkrtz(v[0], v[1]);
            u.h2[1] = __builtin_amdgcn_cvt_pkrtz(v[2], v[3]);
            dst[d] = u.h4;
        }
    }
    __syncthreads();

    const int lane = tid & 63;
    const int w    = tid >> 6;    // 0..7
    const int qg   = w & 3;       // query group of 16
    const int half = w >> 2;      // candidate half
    const int g    = lane >> 4;   // lane owns cands (tile base + 4g..4g+3)
    const int col  = lane & 15;   // query column
    const int qloc = qp * 64 + qg * 16 + col;

    const fp16x4 bfrag = *(const fp16x4*)(sq16 + (size_t)(qg * 16 + col) * 16 + g * 4);

    const __fp16* ap  = sc + (size_t)col * 16 + g * 4;   // + cand*16 halves
    const float*  sqp = ssq + g * 4;
    const uint32_t vg4 = (uint32_t)(g << 2);
    const int hb = half * 512;

    // ---- two independent 256-cand passes (dual sort chains), then one merge ----
    uint32_t A[16], P[16];
    #pragma unroll
    for (int it = 0; it < 2; ++it) {
        uint32_t* D = it ? P : A;
        const int cb0 = hb + it * 256;
        #pragma unroll
        for (int t = 0; t < 16; ++t) {
            const int cb = cb0 + t * 16;
            fp16x4 af = *(const fp16x4*)(ap + (size_t)cb * 16);
            f32x4  sq = *(const f32x4*)(sqp + cb);
            // acc[v] = |c|^2 + 128 - 2<c,q>, cand = cb + 4g + v (one quad)
            f32x4 acc = __builtin_amdgcn_mfma_f32_16x16x16f16(af, bfrag, sq, 0, 0, 0);
            const uint32_t ib = (uint32_t)cb + vg4;
            uint32_t k0 = (__float_as_uint(acc[0]) & 0xFFFFFC00u) | ib;
            uint32_t k1 = (__float_as_uint(acc[1]) & 0xFFFFFC00u) | (ib + 1u);
            uint32_t k2 = (__float_as_uint(acc[2]) & 0xFFFFFC00u) | (ib + 2u);
            uint32_t k3 = (__float_as_uint(acc[3]) & 0xFFFFFC00u) | (ib + 3u);
            D[t] = umn(umn(k0, k1), umn(k2, k3));
        }
        sort16(D);
    }
    keep16(A, P);

    mergeg(A);  // all 4 g-lanes: identical sorted top-16 quad-mins of this half

    // ---- cross-wave (half) merge via dedicated LDS buffer ----
    const int qb = qg * 16 + col;
    if (half == 1) {
        #pragma unroll
        for (int v = 0; v < 4; ++v) smerge[qb][g * 4 + v] = A[g * 4 + v];
    }
    __syncthreads();
    if (half == 1) return;

    {
        uint32_t Q[16];
        #pragma unroll
        for (int i = 0; i < 16; ++i) Q[i] = smerge[qb][i];
        keep16(A, Q);
    }

    // ---- repair: 3 quad-partners per winner; lane g handles winners 4g..4g+3 ----
    union H8 { f32x4 v[2]; fp16x2 h2[8]; };
    H8 qq;
    {
        const f32x4* qf = (const f32x4*)(sq16 + (size_t)(qg * 16 + col) * 16);
        qq.v[0] = qf[0]; qq.v[1] = qf[1];
    }
    uint32_t R[16];
    #pragma unroll
    for (int v = 0; v < 4; ++v) {
        const uint32_t win = sel4(A, g, v);
        const uint32_t wi  = win & 1023u;
        const uint32_t qbse = wi & ~3u;
        const uint32_t wo  = wi & 3u;
        #pragma unroll
        for (int k = 0; k < 3; ++k) {
            const uint32_t o    = (uint32_t)k + (((uint32_t)k >= wo) ? 1u : 0u);
            const uint32_t pidx = qbse + o;
            H8 cc;
            const f32x4* cf = (const f32x4*)(sc + (size_t)pidx * 16);  // -2*c
            cc.v[0] = cf[0]; cc.v[1] = cf[1];
            float s = 0.0f;
            #pragma unroll
            for (int j = 0; j < 8; ++j) {
#if __has_builtin(__builtin_amdgcn_fdot2)
                s = __builtin_amdgcn_fdot2(cc.h2[j], qq.h2[j], s, false);
#else
                s = __builtin_fmaf((float)cc.h2[j][0], (float)qq.h2[j][0], s);
                s = __builtin_fmaf((float)cc.h2[j][1], (float)qq.h2[j][1], s);
#endif
            }
            const float val = s + ssq[pidx];     // |p|^2 + 128 - 2<p,q>
            R[v * 3 + k] = (__float_as_uint(val) & 0xFFFFFC00u) | pidx;
        }
    }
    #pragma unroll
    for (int i = 12; i < 16; ++i) R[i] = 0xFFFFFFFFu;
    sort16(R);
    mergeg(R);       // 48 partners across g-lanes -> lowest 16, all lanes equal
    keep16(A, R);    // final exact top-16 = winners ∪ partners

    // ---- epilogue: lane (g,col) writes int4 #g of src and dst for its query ----
    const int base = seg * L_SEG;
    const int q    = base + qloc;
    int4 sv;
    sv.x = base + (int)(sel4(A, g, 0) & 1023u);
    sv.y = base + (int)(sel4(A, g, 1) & 1023u);
    sv.z = base + (int)(sel4(A, g, 2) & 1023u);
    sv.w = base + (int)(sel4(A, g, 3) & 1023u);
    ((int4*)out)[(size_t)q * 4 + g] = sv;
    ((int4*)out)[(size_t)M_PTS * 4 + (size_t)q * 4 + g] = make_int4(q, q, q, q);
}

extern "C" void kernel_launch(void* const* d_in, const int* in_sizes, int n_in,
                              void* d_out, int out_size, void* d_ws, size_t ws_size,
                              hipStream_t stream) {
    const float* x = (const float*)d_in[0];
    // d_in[1] = segs (int64, all 1024) — static per problem setup, unused.
    int* out = (int*)d_out;
    (void)d_ws; (void)ws_size;
    knn_v10_kernel<<<dim3(1024), dim3(512), 0, stream>>>(x, out);
}